// Round 1
// baseline (511.551 us; speedup 1.0000x reference)
//
#include <hip/hip_runtime.h>
#include <hip/hip_bf16.h>
#include <cstdint>
#include <cstddef>

typedef __bf16 bf8_t __attribute__((ext_vector_type(8)));
typedef __bf16 bf4_t __attribute__((ext_vector_type(4)));
typedef float  f4_t  __attribute__((ext_vector_type(4)));

#define CC 768
#define NROWS 32768           // 8*4096
#define NTOT 25165824         // 32768*768

__device__ __forceinline__ void gld16(const void* g, void* l) {
  __builtin_amdgcn_global_load_lds(
      (const __attribute__((address_space(1))) void*)g,
      (__attribute__((address_space(3))) void*)l, 16, 0, 0);
}

// ---------------- prep kernels ----------------

__global__ void make_cas(__bf16* __restrict__ cas) {
  int idx = blockIdx.x * 256 + threadIdx.x;      // 589824 total
  int i = idx / CC, j = idx - i * CC;
  int ij = (i * j) % CC;                          // exact arg reduction
  float ang = 6.283185307179586f * (float)ij / (float)CC;
  cas[idx] = (__bf16)(__cosf(ang) + __sinf(ang));
}

__global__ void cvt4(const float* __restrict__ x, __bf16* __restrict__ o) {
  int i = (blockIdx.x * 256 + threadIdx.x) * 4;
  float4 v = *(const float4*)(x + i);
  bf4_t r;
  r[0] = (__bf16)v.x; r[1] = (__bf16)v.y; r[2] = (__bf16)v.z; r[3] = (__bf16)v.w;
  *(bf4_t*)(o + i) = r;
}

// pack weights into MFMA B-fragment order: frag[(kt*12+nt)*64 + lane][j]
// B-frag semantics: lane holds B[k = kt*32 + (lane>>4)*8 + j][n = nt*16 + (lane&15)]
__global__ void pack_w1(const float* __restrict__ w1, __bf16* __restrict__ w1f) {
  int f = blockIdx.x * 256 + threadIdx.x;        // < 8*36*64*8 = 147456
  int j = f & 7, lane = (f >> 3) & 63, rest = f >> 9;
  int nt = rest % 12, kt = (rest / 12) % 3, blk = rest / 36;
  int k = kt * 32 + (lane >> 4) * 8 + j;          // 0..95  (input)
  int o = nt * 16 + (lane & 15);                  // 0..191 (output: [real|imag])
  float v = (o < 96) ? w1[(0 * 8 + blk) * 9216 + k * 96 + o]
                     : w1[(1 * 8 + blk) * 9216 + k * 96 + (o - 96)];
  w1f[f] = (__bf16)v;
}

__global__ void pack_w2(const float* __restrict__ w2, __bf16* __restrict__ w2f) {
  int f = blockIdx.x * 256 + threadIdx.x;        // < 8*72*64*8 = 294912
  int j = f & 7, lane = (f >> 3) & 63, rest = f >> 9;
  int nt = rest % 12, kt = (rest / 12) % 6, blk = rest / 72;
  int i = kt * 32 + (lane >> 4) * 8 + j;          // 0..191 (hidden: [ar|ai])
  int o = nt * 16 + (lane & 15);                  // 0..191 (out: [yr|yi])
  float v;
  if (o < 96) v = (i < 96) ?  w2[(0 * 8 + blk) * 9216 + i * 96 + o]
                           : -w2[(1 * 8 + blk) * 9216 + (i - 96) * 96 + o];
  else        v = (i < 96) ?  w2[(1 * 8 + blk) * 9216 + i * 96 + (o - 96)]
                           :  w2[(0 * 8 + blk) * 9216 + (i - 96) * 96 + (o - 96)];
  w2f[f] = (__bf16)v;
}

// ---------------- main GEMM (m97 structure; CAS is symmetric so BT = CAS) ----------------
// mode 0: Cb[row,col] = (bf16)acc       mode 1: Cf[row,col] = acc*scale + Xres[row,col]
__global__ __launch_bounds__(256) void gemm_cas(
    const __bf16* __restrict__ A, const __bf16* __restrict__ BT,
    __bf16* __restrict__ Cb, float* __restrict__ Cf,
    const float* __restrict__ Xres, float scale, int mode)
{
  __shared__ __align__(16) __bf16 sA[128 * 32];
  __shared__ __align__(16) __bf16 sB[128 * 32];
  const int t = threadIdx.x;
  const int lane = t & 63, wid = t >> 6;
  const int wm = (wid >> 1) * 64, wn = (wid & 1) * 64;
  const int m0 = blockIdx.x * 128, n0 = blockIdx.y * 128;
  const int q = lane >> 4, r = lane & 15;
  const int srow = t >> 2, sseg = (t & 3) * 8;
  const __bf16* gA = A + (size_t)(m0 + srow) * CC + sseg;
  const __bf16* gB = BT + (size_t)(n0 + srow) * CC + sseg;
  __bf16* lA = sA + srow * 32 + sseg;
  __bf16* lB = sB + srow * 32 + sseg;

  f4_t acc[4][4] = {};
  for (int k0 = 0; k0 < CC; k0 += 32) {
    __syncthreads();
    gld16(gA + k0, lA);
    gld16(gA + (size_t)64 * CC + k0, lA + 64 * 32);
    gld16(gB + k0, lB);
    gld16(gB + (size_t)64 * CC + k0, lB + 64 * 32);
    __syncthreads();
    bf8_t af[4], bfr[4];
#pragma unroll
    for (int i = 0; i < 4; i++)
      af[i] = *(const bf8_t*)(sA + (wm + i * 16 + r) * 32 + q * 8);
#pragma unroll
    for (int j = 0; j < 4; j++)
      bfr[j] = *(const bf8_t*)(sB + (wn + j * 16 + r) * 32 + q * 8);
#pragma unroll
    for (int i = 0; i < 4; i++)
#pragma unroll
      for (int j = 0; j < 4; j++)
        acc[i][j] = __builtin_amdgcn_mfma_f32_16x16x32_bf16(af[i], bfr[j], acc[i][j], 0, 0, 0);
  }
  // D layout: col = lane&15, row = (lane>>4)*4 + reg
#pragma unroll
  for (int i = 0; i < 4; i++)
#pragma unroll
    for (int j = 0; j < 4; j++) {
      int col = n0 + wn + j * 16 + r;
#pragma unroll
      for (int rr = 0; rr < 4; rr++) {
        int row = m0 + wm + i * 16 + q * 4 + rr;
        size_t off = (size_t)row * CC + col;
        if (mode == 0) Cb[off] = (__bf16)acc[i][j][rr];
        else           Cf[off] = acc[i][j][rr] * scale + Xres[off];
      }
    }
}

// ---------------- fused block-diagonal complex MLP + softshrink ----------------
// workgroup: 64 rows (4 waves x 16 rows) x one block k.  Z[row, blk*96+c] = ss(yr)-ss(yi)
__global__ __launch_bounds__(256) void mlp_kernel(
    const __bf16* __restrict__ V,
    const __bf16* __restrict__ w1f, const __bf16* __restrict__ w2f,
    const float* __restrict__ b1, const float* __restrict__ b2,
    __bf16* __restrict__ Z)
{
  __shared__ __align__(16) __bf16 hl[4][16 * 200];   // 192 hidden + 8 pad (bank-conflict-free reads)
  __shared__ __align__(16) __bf16 zl[4][16 * 96];
  const int t = threadIdx.x, lane = t & 63, w = t >> 6;
  const int blk = blockIdx.y;
  const int r0 = blockIdx.x * 64 + w * 16;
  const int q = lane >> 4, r = lane & 15;

  // phase 1: H = relu([V_k W1r + b1r | V_k W1i + b1i])
  f4_t h[12] = {};
  const __bf16* w1b = w1f + (size_t)blk * (36 * 64 * 8);
#pragma unroll
  for (int kt = 0; kt < 3; kt++) {
    bf8_t a = *(const bf8_t*)(V + (size_t)(r0 + r) * CC + blk * 96 + kt * 32 + q * 8);
#pragma unroll
    for (int nt = 0; nt < 12; nt++) {
      bf8_t b = *(const bf8_t*)(w1b + ((kt * 12 + nt) * 64 + lane) * 8);
      h[nt] = __builtin_amdgcn_mfma_f32_16x16x32_bf16(a, b, h[nt], 0, 0, 0);
    }
  }
#pragma unroll
  for (int nt = 0; nt < 12; nt++) {
    int c = nt * 16 + r;
    float bb = (c < 96) ? b1[blk * 96 + c] : b1[768 + blk * 96 + (c - 96)];
#pragma unroll
    for (int rr = 0; rr < 4; rr++) {
      float v = h[nt][rr] + bb;
      v = v > 0.f ? v : 0.f;
      hl[w][(q * 4 + rr) * 200 + c] = (__bf16)v;   // D-layout -> row-major [row][hidden]
    }
  }
  // same-wave LDS dependency only; compiler inserts lgkmcnt waits, no barrier needed

  // phase 2: Y = H @ W2pack + b2 ; z = ss(yr) - ss(yi)
  f4_t y[12] = {};
  const __bf16* w2b = w2f + (size_t)blk * (72 * 64 * 8);
#pragma unroll
  for (int kt = 0; kt < 6; kt++) {
    bf8_t a = *(const bf8_t*)(&hl[w][r * 200 + kt * 32 + q * 8]);  // A-layout read
#pragma unroll
    for (int nt = 0; nt < 12; nt++) {
      bf8_t b = *(const bf8_t*)(w2b + ((kt * 12 + nt) * 64 + lane) * 8);
      y[nt] = __builtin_amdgcn_mfma_f32_16x16x32_bf16(a, b, y[nt], 0, 0, 0);
    }
  }
#pragma unroll
  for (int nt = 0; nt < 6; nt++) {
    int c = nt * 16 + r;
    float br = b2[blk * 96 + c];
    float bi = b2[768 + blk * 96 + c];
#pragma unroll
    for (int rr = 0; rr < 4; rr++) {
      float yr = y[nt][rr] + br;
      float yi = y[nt + 6][rr] + bi;
      float ar = fabsf(yr) - 0.01f; ar = ar > 0.f ? ar : 0.f; ar = copysignf(ar, yr);
      float ai = fabsf(yi) - 0.01f; ai = ai > 0.f ? ai : 0.f; ai = copysignf(ai, yi);
      zl[w][(q * 4 + rr) * 96 + c] = (__bf16)(ar - ai);
    }
  }
  // coalesced copy-out: 16 rows x 96 bf16 (= 48 dwords/row)
  const uint32_t* zsrc = (const uint32_t*)&zl[w][0];
  if (lane < 48) {
#pragma unroll
    for (int row = 0; row < 16; row++) {
      uint32_t* dst = (uint32_t*)(Z + (size_t)(r0 + row) * CC + blk * 96);
      dst[lane] = zsrc[row * 48 + lane];
    }
  }
}

// ---------------- launch ----------------

extern "C" void kernel_launch(void* const* d_in, const int* in_sizes, int n_in,
                              void* d_out, int out_size, void* d_ws, size_t ws_size,
                              hipStream_t stream) {
  const float* x  = (const float*)d_in[0];
  const float* w1 = (const float*)d_in[1];
  const float* b1 = (const float*)d_in[2];
  const float* w2 = (const float*)d_in[3];
  const float* b2 = (const float*)d_in[4];
  float* out = (float*)d_out;

  char* ws = (char*)d_ws;
  size_t off = 0;
  auto alloc = [&](size_t bytes) {
    char* p = ws + off;
    off += (bytes + 255) & ~(size_t)255;
    return p;
  };
  __bf16* casb = (__bf16*)alloc((size_t)CC * CC * 2);        // 1.18 MB
  __bf16* w1f  = (__bf16*)alloc((size_t)8 * 36 * 64 * 8 * 2);
  __bf16* w2f  = (__bf16*)alloc((size_t)8 * 72 * 64 * 8 * 2);
  __bf16* xb   = (__bf16*)alloc((size_t)NTOT * 2);           // 50.3 MB (reused as Z)
  __bf16* vv   = (__bf16*)alloc((size_t)NTOT * 2);           // 50.3 MB

  make_cas<<<2304, 256, 0, stream>>>(casb);
  cvt4<<<24576, 256, 0, stream>>>(x, xb);
  pack_w1<<<576, 256, 0, stream>>>(w1, w1f);
  pack_w2<<<1152, 256, 0, stream>>>(w2, w2f);

  // V = Xbf16 @ CAS   (CAS symmetric => BT = CAS)
  gemm_cas<<<dim3(256, 6), 256, 0, stream>>>(xb, casb, vv, nullptr, nullptr, 0.f, 0);
  // Z (into xb) = softshrink-MLP(V)
  mlp_kernel<<<dim3(512, 8), 256, 0, stream>>>(vv, w1f, w2f, b1, b2, xb);
  // OUT = Z @ CAS / n_tot + X
  gemm_cas<<<dim3(256, 6), 256, 0, stream>>>(xb, casb, nullptr, out, x, 1.0f / 25165824.0f, 1);
}

// Round 2
// 423.508 us; speedup vs baseline: 1.2079x; 1.2079x over previous
//
#include <hip/hip_runtime.h>
#include <hip/hip_bf16.h>
#include <cstdint>
#include <cstddef>

typedef __bf16 bf8_t __attribute__((ext_vector_type(8)));
typedef __bf16 bf4_t __attribute__((ext_vector_type(4)));
typedef float  f4_t  __attribute__((ext_vector_type(4)));

#define CC 768
#define NROWS 32768           // 8*4096
#define NTOT 25165824         // 32768*768

__device__ __forceinline__ void gld16(const void* g, void* l) {
  __builtin_amdgcn_global_load_lds(
      (const __attribute__((address_space(1))) void*)g,
      (__attribute__((address_space(3))) void*)l, 16, 0, 0);
}

// ---------------- prep kernels ----------------

__global__ void make_cas(__bf16* __restrict__ cas) {
  int idx = blockIdx.x * 256 + threadIdx.x;      // 589824 total
  int i = idx / CC, j = idx - i * CC;
  int ij = (i * j) % CC;                          // exact arg reduction
  float ang = 6.283185307179586f * (float)ij / (float)CC;
  cas[idx] = (__bf16)(__cosf(ang) + __sinf(ang));
}

__global__ void cvt4(const float* __restrict__ x, __bf16* __restrict__ o) {
  int i = (blockIdx.x * 256 + threadIdx.x) * 4;
  float4 v = *(const float4*)(x + i);
  bf4_t r;
  r[0] = (__bf16)v.x; r[1] = (__bf16)v.y; r[2] = (__bf16)v.z; r[3] = (__bf16)v.w;
  *(bf4_t*)(o + i) = r;
}

// pack weights into MFMA B-fragment order: frag[(kt*12+nt)*64 + lane][j]
// B-frag semantics: lane holds B[k = kt*32 + (lane>>4)*8 + j][n = nt*16 + (lane&15)]
__global__ void pack_w1(const float* __restrict__ w1, __bf16* __restrict__ w1f) {
  int f = blockIdx.x * 256 + threadIdx.x;        // < 8*36*64*8 = 147456
  int j = f & 7, lane = (f >> 3) & 63, rest = f >> 9;
  int nt = rest % 12, kt = (rest / 12) % 3, blk = rest / 36;
  int k = kt * 32 + (lane >> 4) * 8 + j;          // 0..95  (input)
  int o = nt * 16 + (lane & 15);                  // 0..191 (output: [real|imag])
  float v = (o < 96) ? w1[(0 * 8 + blk) * 9216 + k * 96 + o]
                     : w1[(1 * 8 + blk) * 9216 + k * 96 + (o - 96)];
  w1f[f] = (__bf16)v;
}

__global__ void pack_w2(const float* __restrict__ w2, __bf16* __restrict__ w2f) {
  int f = blockIdx.x * 256 + threadIdx.x;        // < 8*72*64*8 = 294912
  int j = f & 7, lane = (f >> 3) & 63, rest = f >> 9;
  int nt = rest % 12, kt = (rest / 12) % 6, blk = rest / 72;
  int i = kt * 32 + (lane >> 4) * 8 + j;          // 0..191 (hidden: [ar|ai])
  int o = nt * 16 + (lane & 15);                  // 0..191 (out: [yr|yi])
  float v;
  if (o < 96) v = (i < 96) ?  w2[(0 * 8 + blk) * 9216 + i * 96 + o]
                           : -w2[(1 * 8 + blk) * 9216 + (i - 96) * 96 + o];
  else        v = (i < 96) ?  w2[(1 * 8 + blk) * 9216 + i * 96 + (o - 96)]
                           :  w2[(0 * 8 + blk) * 9216 + (i - 96) * 96 + (o - 96)];
  w2f[f] = (__bf16)v;
}

// ---------------- main GEMM (m97 structure; CAS is symmetric so BT = CAS) ----------------
// mode 0: Cb[row,col] = (bf16)acc       mode 1: Cf[row,col] = acc*scale + Xres[row,col]
__global__ __launch_bounds__(256) void gemm_cas(
    const __bf16* __restrict__ A, const __bf16* __restrict__ BT,
    __bf16* __restrict__ Cb, float* __restrict__ Cf,
    const float* __restrict__ Xres, float scale, int mode)
{
  __shared__ __align__(16) __bf16 sA[128 * 32];
  __shared__ __align__(16) __bf16 sB[128 * 32];
  const int t = threadIdx.x;
  const int lane = t & 63, wid = t >> 6;
  const int wm = (wid >> 1) * 64, wn = (wid & 1) * 64;
  const int m0 = blockIdx.x * 128, n0 = blockIdx.y * 128;
  const int q = lane >> 4, r = lane & 15;
  const int srow = t >> 2, sseg = (t & 3) * 8;
  const __bf16* gA = A + (size_t)(m0 + srow) * CC + sseg;
  const __bf16* gB = BT + (size_t)(n0 + srow) * CC + sseg;
  __bf16* lA = sA + srow * 32 + sseg;
  __bf16* lB = sB + srow * 32 + sseg;

  f4_t acc[4][4] = {};
  for (int k0 = 0; k0 < CC; k0 += 32) {
    __syncthreads();
    gld16(gA + k0, lA);
    gld16(gA + (size_t)64 * CC + k0, lA + 64 * 32);
    gld16(gB + k0, lB);
    gld16(gB + (size_t)64 * CC + k0, lB + 64 * 32);
    __syncthreads();
    bf8_t af[4], bfr[4];
#pragma unroll
    for (int i = 0; i < 4; i++)
      af[i] = *(const bf8_t*)(sA + (wm + i * 16 + r) * 32 + q * 8);
#pragma unroll
    for (int j = 0; j < 4; j++)
      bfr[j] = *(const bf8_t*)(sB + (wn + j * 16 + r) * 32 + q * 8);
#pragma unroll
    for (int i = 0; i < 4; i++)
#pragma unroll
      for (int j = 0; j < 4; j++)
        acc[i][j] = __builtin_amdgcn_mfma_f32_16x16x32_bf16(af[i], bfr[j], acc[i][j], 0, 0, 0);
  }
  // D layout: col = lane&15, row = (lane>>4)*4 + reg
#pragma unroll
  for (int i = 0; i < 4; i++)
#pragma unroll
    for (int j = 0; j < 4; j++) {
      int col = n0 + wn + j * 16 + r;
#pragma unroll
      for (int rr = 0; rr < 4; rr++) {
        int row = m0 + wm + i * 16 + q * 4 + rr;
        size_t off = (size_t)row * CC + col;
        if (mode == 0) Cb[off] = (__bf16)acc[i][j][rr];
        else           Cf[off] = acc[i][j][rr] * scale + Xres[off];
      }
    }
}

// ---------------- fused block-diagonal complex MLP + softshrink (v2) ----------------
// Workgroup: 384 threads = 6 waves, 128 rows x 1 block. Weights held in REGISTERS:
// wave w owns hidden tiles {2w, 2w+1} (phase 1) and output-col tile w (+ imag tile w+6)
// (phase 2). Per wave only 18 x 1KB fragment loads, once -> weight L2 traffic drops
// 8x vs v1 (1.77 GB -> 221 MB). Rows stream in two half-passes through a 64-row LDS
// H buffer (stride 200: 16B-aligned, 8-banks-of-8 pattern like m97's sA).
__global__ __launch_bounds__(384, 3) void mlp_kernel(
    const __bf16* __restrict__ V,
    const __bf16* __restrict__ w1f, const __bf16* __restrict__ w2f,
    const float* __restrict__ b1, const float* __restrict__ b2,
    __bf16* __restrict__ Z)
{
  __shared__ __align__(16) __bf16 H[64 * 200];    // 25.6 KB
  __shared__ __align__(16) __bf16 zl[64 * 96];    // 12.3 KB
  const int t = threadIdx.x, lane = t & 63, w = t >> 6;   // w in 0..5
  const int blk = blockIdx.y;
  const int r0 = blockIdx.x * 128;
  const int q = lane >> 4, r = lane & 15;

  // ---- load this wave's weight fragments into registers (once) ----
  const __bf16* w1b = w1f + (size_t)blk * (36 * 64 * 8);
  const __bf16* w2b = w2f + (size_t)blk * (72 * 64 * 8);
  bf8_t w1r[3][2], w2r[6][2];
#pragma unroll
  for (int kt = 0; kt < 3; kt++)
#pragma unroll
    for (int j = 0; j < 2; j++)
      w1r[kt][j] = *(const bf8_t*)(w1b + ((size_t)(kt * 12 + 2 * w + j) * 64 + lane) * 8);
#pragma unroll
  for (int kt = 0; kt < 6; kt++) {
    w2r[kt][0] = *(const bf8_t*)(w2b + ((size_t)(kt * 12 + w) * 64 + lane) * 8);
    w2r[kt][1] = *(const bf8_t*)(w2b + ((size_t)(kt * 12 + w + 6) * 64 + lane) * 8);
  }
  // biases for this wave's tiles
  float bb[2];
#pragma unroll
  for (int j = 0; j < 2; j++) {
    int c = (2 * w + j) * 16 + r;
    bb[j] = (c < 96) ? b1[blk * 96 + c] : b1[768 + blk * 96 + (c - 96)];
  }
  const float br = b2[blk * 96 + w * 16 + r];
  const float bi = b2[768 + blk * 96 + w * 16 + r];

  for (int h = 0; h < 2; h++) {
    const int rbase = r0 + h * 64;
    // ---- phase 1: H[0:64][192] = relu(V W1 + b1), wave w writes cols [32w,32w+32) ----
#pragma unroll
    for (int rt = 0; rt < 4; rt++) {
      const __bf16* vp = V + (size_t)(rbase + rt * 16 + r) * CC + blk * 96 + q * 8;
      f4_t acc0 = {}, acc1 = {};
#pragma unroll
      for (int kt = 0; kt < 3; kt++) {
        bf8_t a = *(const bf8_t*)(vp + kt * 32);
        acc0 = __builtin_amdgcn_mfma_f32_16x16x32_bf16(a, w1r[kt][0], acc0, 0, 0, 0);
        acc1 = __builtin_amdgcn_mfma_f32_16x16x32_bf16(a, w1r[kt][1], acc1, 0, 0, 0);
      }
#pragma unroll
      for (int j = 0; j < 2; j++) {
        int c = (2 * w + j) * 16 + r;
        f4_t* ap = j ? &acc1 : &acc0;
#pragma unroll
        for (int rr = 0; rr < 4; rr++) {
          float v = (*ap)[rr] + bb[j];
          H[(rt * 16 + q * 4 + rr) * 200 + c] = (__bf16)(v > 0.f ? v : 0.f);
        }
      }
    }
    __syncthreads();
    // ---- phase 2: y = H W2pack + b2; z = ss(yr) - ss(yi); wave w -> z cols [16w,16w+16) ----
#pragma unroll
    for (int rt = 0; rt < 4; rt++) {
      f4_t ar = {}, ai = {};
#pragma unroll
      for (int kt = 0; kt < 6; kt++) {
        bf8_t a = *(const bf8_t*)(&H[(rt * 16 + r) * 200 + kt * 32 + q * 8]);
        ar = __builtin_amdgcn_mfma_f32_16x16x32_bf16(a, w2r[kt][0], ar, 0, 0, 0);
        ai = __builtin_amdgcn_mfma_f32_16x16x32_bf16(a, w2r[kt][1], ai, 0, 0, 0);
      }
#pragma unroll
      for (int rr = 0; rr < 4; rr++) {
        float yr = ar[rr] + br, yi = ai[rr] + bi;
        float sr = fabsf(yr) - 0.01f; sr = sr > 0.f ? copysignf(sr, yr) : 0.f;
        float si = fabsf(yi) - 0.01f; si = si > 0.f ? copysignf(si, yi) : 0.f;
        zl[(rt * 16 + q * 4 + rr) * 96 + w * 16 + r] = (__bf16)(sr - si);
      }
    }
    __syncthreads();
    // ---- copy-out: 64 rows x 48 dwords, coalesced ----
    {
      const uint32_t* zsrc = (const uint32_t*)zl;
      int cdw = t % 48, crow = t / 48;            // 8 rows per pass
#pragma unroll
      for (int it = 0; it < 8; it++) {
        int row = it * 8 + crow;
        uint32_t* dst = (uint32_t*)(Z + (size_t)(rbase + row) * CC + blk * 96);
        dst[cdw] = zsrc[row * 48 + cdw];
      }
    }
    __syncthreads();   // protect H/zl before next half-pass
  }
}

// ---------------- launch ----------------

extern "C" void kernel_launch(void* const* d_in, const int* in_sizes, int n_in,
                              void* d_out, int out_size, void* d_ws, size_t ws_size,
                              hipStream_t stream) {
  const float* x  = (const float*)d_in[0];
  const float* w1 = (const float*)d_in[1];
  const float* b1 = (const float*)d_in[2];
  const float* w2 = (const float*)d_in[3];
  const float* b2 = (const float*)d_in[4];
  float* out = (float*)d_out;

  char* ws = (char*)d_ws;
  size_t off = 0;
  auto alloc = [&](size_t bytes) {
    char* p = ws + off;
    off += (bytes + 255) & ~(size_t)255;
    return p;
  };
  __bf16* casb = (__bf16*)alloc((size_t)CC * CC * 2);        // 1.18 MB
  __bf16* w1f  = (__bf16*)alloc((size_t)8 * 36 * 64 * 8 * 2);
  __bf16* w2f  = (__bf16*)alloc((size_t)8 * 72 * 64 * 8 * 2);
  __bf16* xb   = (__bf16*)alloc((size_t)NTOT * 2);           // 50.3 MB (reused as Z)
  __bf16* vv   = (__bf16*)alloc((size_t)NTOT * 2);           // 50.3 MB

  make_cas<<<2304, 256, 0, stream>>>(casb);
  cvt4<<<24576, 256, 0, stream>>>(x, xb);
  pack_w1<<<576, 256, 0, stream>>>(w1, w1f);
  pack_w2<<<1152, 256, 0, stream>>>(w2, w2f);

  // V = Xbf16 @ CAS   (CAS symmetric => BT = CAS)
  gemm_cas<<<dim3(256, 6), 256, 0, stream>>>(xb, casb, vv, nullptr, nullptr, 0.f, 0);
  // Z (into xb) = softshrink-MLP(V)
  mlp_kernel<<<dim3(256, 8), 384, 0, stream>>>(vv, w1f, w2f, b1, b2, xb);
  // OUT = Z @ CAS / n_tot + X
  gemm_cas<<<dim3(256, 6), 256, 0, stream>>>(xb, casb, nullptr, out, x, 1.0f / 25165824.0f, 1);
}